// Round 3
// baseline (3780.764 us; speedup 1.0000x reference)
//
#include <hip/hip_runtime.h>
#include <hip/hip_bf16.h>
#include <math.h>

typedef __bf16 bf16x8 __attribute__((ext_vector_type(8)));
typedef float f32x4 __attribute__((ext_vector_type(4)));

#define S_LEN 128
#define BATCH 32
#define E2C 1024
#define DH 512
#define AH 32
#define EMBD 256
#define VOC 32000
#define TMAX 48
#define NCHUNK 125   /* VOC / 256 */

#define MFMA16(a, b, c) __builtin_amdgcn_mfma_f32_16x16x32_bf16((a), (b), (c), 0, 0, 0)

// Split 8 consecutive f32 into bf16 hi + bf16 lo (x = hi + lo + O(2^-18 x)).
__device__ __forceinline__ void split8(const float* __restrict__ p,
                                       bf16x8& hi, bf16x8& lo) {
  const f32x4 v0 = *(const f32x4*)p;
  const f32x4 v1 = *(const f32x4*)(p + 4);
  float t[8] = {v0[0], v0[1], v0[2], v0[3], v1[0], v1[1], v1[2], v1[3]};
  #pragma unroll
  for (int i = 0; i < 8; i++) {
    const __bf16 h = (__bf16)t[i];
    hi[i] = h;
    lo[i] = (__bf16)(t[i] - (float)h);
  }
}

// ---------------------------------------------------------------------------
// K_init: zero the h-state block (hf0|hh0|hl0 = 131072 B = 32768 u32).
// ---------------------------------------------------------------------------
__global__ __launch_bounds__(256) void k_init(unsigned int* __restrict__ p) {
  p[blockIdx.x * 256 + threadIdx.x] = 0u;
}

// ---------------------------------------------------------------------------
// K0: encW1[s,b,j] = sum_k enc[s,b,k] * W1[j, DH+k]   (hoisted out of t-loop)
// ---------------------------------------------------------------------------
__global__ __launch_bounds__(256) void k_encw1(const float* __restrict__ enc,
                                               const float* __restrict__ W1,
                                               float* __restrict__ encW1) {
  __shared__ float el[E2C];
  __shared__ float red[256];
  const int tid = threadIdx.x;
  const int blk = blockIdx.x;                       // s*BATCH + b
  for (int i = 0; i < 4; i++)
    el[tid + i * 256] = enc[(size_t)blk * E2C + tid + i * 256];
  __syncthreads();
  const int j = tid >> 3, c = tid & 7;
  const float* wrow = W1 + (size_t)j * (DH + E2C) + DH;
  float p = 0.f;
  for (int k = c * 128; k < c * 128 + 128; k++) p += el[k] * wrow[k];
  red[tid] = p;
  __syncthreads();
  if (c < 4) red[tid] += red[tid + 4];
  __syncthreads();
  if (c < 2) red[tid] += red[tid + 2];
  __syncthreads();
  if (c == 0) encW1[(size_t)blk * AH + j] = red[tid] + red[tid + 1];
}

// ---------------------------------------------------------------------------
// K1: per-batch block. (a) finalize previous argmax -> embedding into x,
//     (b) hW1, (c) scores+softmax, (d) context -> x hi/lo split.
// ---------------------------------------------------------------------------
__global__ __launch_bounds__(256) void k_attn(int t,
    const float* __restrict__ enc, const int* __restrict__ sos,
    const float* __restrict__ emb,
    const float* __restrict__ W1, const float* __restrict__ b1,
    const float* __restrict__ W2, const float* __restrict__ b2,
    const float* __restrict__ encW1,
    const float* __restrict__ hf,
    const float* __restrict__ pval, const int* __restrict__ pidx,
    __bf16* __restrict__ xh, __bf16* __restrict__ xl) {
  __shared__ float hs[DH];
  __shared__ float hw[AH];
  __shared__ float sc[S_LEN];
  __shared__ float red[256];
  __shared__ int ri[128];
  __shared__ int s_id;
  const int tid = threadIdx.x;
  const int b = blockIdx.x;

  // Phase A: token id -> embedding rows of x (hi/lo split of f32 emb)
  if (t == 0) {
    if (tid == 0) s_id = sos[0];
  } else {
    if (tid < 128) {
      if (tid < NCHUNK) { red[tid] = pval[b * 128 + tid]; ri[tid] = pidx[b * 128 + tid]; }
      else              { red[tid] = -INFINITY;           ri[tid] = 0x7fffffff; }
    }
    __syncthreads();
    for (int off = 64; off >= 1; off >>= 1) {
      if (tid < off) {
        const float ov = red[tid + off]; const int oi = ri[tid + off];
        if (ov > red[tid] || (ov == red[tid] && oi < ri[tid])) { red[tid] = ov; ri[tid] = oi; }
      }
      __syncthreads();
    }
    if (tid == 0) s_id = ri[0];
  }
  __syncthreads();
  {
    int id = s_id;
    if (id < 0 || id >= VOC) id = 0;   // never fault on bad feedback
    const float e = emb[(size_t)id * EMBD + tid];
    const __bf16 eh = (__bf16)e;
    xh[b * 1280 + 1024 + tid] = eh;
    xl[b * 1280 + 1024 + tid] = (__bf16)(e - (float)eh);
  }

  // Phase B: hW1[j] = h[b,:] . W1[j,0:DH] + b1[j]
  hs[tid] = hf[b * DH + tid];
  hs[tid + 256] = hf[b * DH + tid + 256];
  __syncthreads();
  {
    const int j = tid >> 3, c = tid & 7;
    const float* wrow = W1 + (size_t)j * (DH + E2C);
    float p = 0.f;
    for (int k = c * 64; k < c * 64 + 64; k++) p += hs[k] * wrow[k];
    red[tid] = p;
  }
  __syncthreads();
  if ((tid & 7) < 4) red[tid] += red[tid + 4];
  __syncthreads();
  if ((tid & 7) < 2) red[tid] += red[tid + 2];
  __syncthreads();
  if ((tid & 7) == 0) hw[tid >> 3] = red[tid] + red[tid + 1] + b1[tid >> 3];
  __syncthreads();

  // Phase C: scores + softmax over S
  float ex = 0.f;
  if (tid < S_LEN) {
    const float* ew = encW1 + ((size_t)tid * BATCH + b) * AH;
    float sum = b2[0];
    #pragma unroll
    for (int j = 0; j < AH; j++) {
      const float v = ew[j] + hw[j];
      sum += fmaxf(v, 0.f) * W2[j];
    }
    sc[tid] = sum;
  }
  __syncthreads();
  if (tid < 128) red[tid] = sc[tid];
  __syncthreads();
  for (int off = 64; off >= 1; off >>= 1) {
    if (tid < off) red[tid] = fmaxf(red[tid], red[tid + off]);
    __syncthreads();
  }
  const float mx = red[0];
  __syncthreads();
  if (tid < 128) { ex = expf(sc[tid] - mx); red[tid] = ex; }
  __syncthreads();
  for (int off = 64; off >= 1; off >>= 1) {
    if (tid < off) red[tid] += red[tid + off];
    __syncthreads();
  }
  const float ssum = red[0];
  if (tid < 128) sc[tid] = ex / ssum;
  __syncthreads();

  // Phase D: context[e] = sum_s attn[s]*enc[s,b,e]; hi/lo split into x
  const int e0 = tid * 4;
  float a0 = 0.f, a1 = 0.f, a2 = 0.f, a3 = 0.f;
  for (int s = 0; s < S_LEN; s++) {
    const float wgt = sc[s];
    const f32x4 ev = *(const f32x4*)(enc + ((size_t)s * BATCH + b) * E2C + e0);
    a0 += wgt * ev[0];
    a1 += wgt * ev[1];
    a2 += wgt * ev[2];
    a3 += wgt * ev[3];
  }
  float vals[4] = {a0, a1, a2, a3};
  #pragma unroll
  for (int i = 0; i < 4; i++) {
    const float v = vals[i];
    const __bf16 hi = (__bf16)v;
    xh[b * 1280 + e0 + i] = hi;
    xl[b * 1280 + e0 + i] = (__bf16)(v - (float)hi);
  }
}

// ---------------------------------------------------------------------------
// K2: GRU cell. Grid = 32 blocks (16 d-rows each), 4 waves = K-split-4 over
// the concatenated K=1792 ([x@Wih | h@Whh]). Separate accumulators for the
// n-gate's input/hidden halves (r gates only ghn). LDS 4-way reduce + epilogue.
// i<10 <=> Wih region (wv*32 < 128, so the branch is wave-independent and
// compile-time under full unroll -> static acc indexing, no spills).
// ---------------------------------------------------------------------------
__global__ __launch_bounds__(256) void k_gru(
    const __bf16* __restrict__ xh, const __bf16* __restrict__ xl,
    const float* __restrict__ Wih, const float* __restrict__ bih,
    const float* __restrict__ Whh, const float* __restrict__ bhh,
    const float* __restrict__ hf_in, const __bf16* __restrict__ hh_in,
    const __bf16* __restrict__ hl_in,
    float* __restrict__ hf_out, __bf16* __restrict__ hh_out,
    __bf16* __restrict__ hl_out) {
  __shared__ float lds[4][8][256];
  const int tid = threadIdx.x;
  const int wv = tid >> 6;
  const int lane = tid & 63;
  const int q = lane >> 4;
  const int ln = lane & 15;
  const int d = blockIdx.x * 16 + ln;          // weight row (n index)

  f32x4 acc[4][2];                             // t: 0=r 1=z 2=n_i 3=n_h; [mt]
  const f32x4 z4 = {0.f, 0.f, 0.f, 0.f};
  #pragma unroll
  for (int t = 0; t < 4; t++) { acc[t][0] = z4; acc[t][1] = z4; }

  #pragma unroll
  for (int i = 0; i < 14; i++) {
    const int kk = wv * 32 + i * 128;
    const int ka = kk + q * 8;
    bf16x8 ah0, al0, ah1, al1;
    if (i < 10) {
      ah0 = *(const bf16x8*)(xh + ln * 1280 + ka);
      ah1 = *(const bf16x8*)(xh + (16 + ln) * 1280 + ka);
      al0 = *(const bf16x8*)(xl + ln * 1280 + ka);
      al1 = *(const bf16x8*)(xl + (16 + ln) * 1280 + ka);
    } else {
      const int kb = ka - 1280;
      ah0 = *(const bf16x8*)(hh_in + ln * 512 + kb);
      ah1 = *(const bf16x8*)(hh_in + (16 + ln) * 512 + kb);
      al0 = *(const bf16x8*)(hl_in + ln * 512 + kb);
      al1 = *(const bf16x8*)(hl_in + (16 + ln) * 512 + kb);
    }
    #pragma unroll
    for (int g = 0; g < 3; g++) {
      bf16x8 bh, bl;
      if (i < 10) split8(Wih + (size_t)(g * 512 + d) * 1280 + ka, bh, bl);
      else        split8(Whh + (size_t)(g * 512 + d) * 512 + (ka - 1280), bh, bl);
      const int t = (g < 2) ? g : ((i < 10) ? 2 : 3);
      acc[t][0] = MFMA16(ah0, bh, acc[t][0]);
      acc[t][0] = MFMA16(al0, bh, acc[t][0]);
      acc[t][0] = MFMA16(ah0, bl, acc[t][0]);
      acc[t][1] = MFMA16(ah1, bh, acc[t][1]);
      acc[t][1] = MFMA16(al1, bh, acc[t][1]);
      acc[t][1] = MFMA16(ah1, bl, acc[t][1]);
    }
  }

  // stage per-wave partials: tile tt = t*2+mt, elem = (row)*16 + col
  #pragma unroll
  for (int t = 0; t < 4; t++)
    #pragma unroll
    for (int mt = 0; mt < 2; mt++)
      #pragma unroll
      for (int r = 0; r < 4; r++)
        lds[wv][t * 2 + mt][(q * 4 + r) * 16 + ln] = acc[t][mt][r];
  __syncthreads();
  for (int idx = tid; idx < 8 * 256; idx += 256) {
    const int tt = idx >> 8, e = idx & 255;
    lds[0][tt][e] += lds[1][tt][e] + lds[2][tt][e] + lds[3][tt][e];
  }
  __syncthreads();

  // epilogue: (b, dd) pairs; D row = batch, col = d
  for (int u = tid; u < 512; u += 256) {
    const int b = u >> 4, dd = u & 15;
    const int mt = b >> 4;
    const int e = (b & 15) * 16 + dd;
    const int dg = blockIdx.x * 16 + dd;
    const float rp  = lds[0][0 * 2 + mt][e] + bih[dg]        + bhh[dg];
    const float zp  = lds[0][1 * 2 + mt][e] + bih[DH + dg]   + bhh[DH + dg];
    const float gin = lds[0][2 * 2 + mt][e] + bih[2 * DH + dg];
    const float ghn = lds[0][3 * 2 + mt][e] + bhh[2 * DH + dg];
    const float rg = 1.f / (1.f + expf(-rp));
    const float zg = 1.f / (1.f + expf(-zp));
    const float ng = tanhf(gin + rg * ghn);
    const float hp = hf_in[b * DH + dg];
    const float hn = (1.f - zg) * ng + zg * hp;
    hf_out[b * DH + dg] = hn;
    const __bf16 hi = (__bf16)hn;
    hh_out[b * DH + dg] = hi;
    hl_out[b * DH + dg] = (__bf16)(hn - (float)hi);
  }
}

// ---------------------------------------------------------------------------
// K3: logits = h_new @ Wo.T + bo (f32 out), per-256-vocab-chunk argmax.
// Wo split to bf16 hi/lo on the fly; 3 MFMA passes per tile pair.
// ---------------------------------------------------------------------------
__global__ __launch_bounds__(256) void k_logits(
    const __bf16* __restrict__ hh, const __bf16* __restrict__ hl,
    const float* __restrict__ Wo, const float* __restrict__ bo,
    float* __restrict__ outp, float* __restrict__ pval, int* __restrict__ pidx) {
  const int tid = threadIdx.x;
  const int w = tid >> 6;
  const int lane = tid & 63;
  const int quad = lane >> 4;
  const int ln = lane & 15;
  const int v0 = blockIdx.x * 256;

  f32x4 acc[2][4];
  const f32x4 z4 = {0.f, 0.f, 0.f, 0.f};
  #pragma unroll
  for (int m = 0; m < 2; m++)
    for (int n = 0; n < 4; n++) acc[m][n] = z4;

  for (int kk = 0; kk < 512; kk += 32) {
    const int ka = kk + quad * 8;
    const bf16x8 fh0 = *(const bf16x8*)(hh + ln * 512 + ka);
    const bf16x8 fh1 = *(const bf16x8*)(hh + (16 + ln) * 512 + ka);
    const bf16x8 fl0 = *(const bf16x8*)(hl + ln * 512 + ka);
    const bf16x8 fl1 = *(const bf16x8*)(hl + (16 + ln) * 512 + ka);
    #pragma unroll
    for (int nt = 0; nt < 4; nt++) {
      const int vr = v0 + (w * 4 + nt) * 16 + ln;
      bf16x8 bh, bl;
      split8(Wo + (size_t)vr * 512 + ka, bh, bl);
      acc[0][nt] = MFMA16(fh0, bh, acc[0][nt]);
      acc[0][nt] = MFMA16(fl0, bh, acc[0][nt]);
      acc[0][nt] = MFMA16(fh0, bl, acc[0][nt]);
      acc[1][nt] = MFMA16(fh1, bh, acc[1][nt]);
      acc[1][nt] = MFMA16(fl1, bh, acc[1][nt]);
      acc[1][nt] = MFMA16(fh1, bl, acc[1][nt]);
    }
  }

  float bv[2][4]; int bi[2][4];
  #pragma unroll
  for (int m = 0; m < 2; m++)
    for (int r = 0; r < 4; r++) { bv[m][r] = -INFINITY; bi[m][r] = 0x7fffffff; }

  #pragma unroll
  for (int nt = 0; nt < 4; nt++) {             // ascending v -> strict > keeps lowest idx
    const int v = v0 + (w * 4 + nt) * 16 + ln;
    const float bias = bo[v];
    #pragma unroll
    for (int mt = 0; mt < 2; mt++) {
      #pragma unroll
      for (int r = 0; r < 4; r++) {
        const float val = acc[mt][nt][r] + bias;
        const int b = mt * 16 + quad * 4 + r;
        outp[(size_t)b * VOC + v] = val;
        if (val > bv[mt][r]) { bv[mt][r] = val; bi[mt][r] = v; }
      }
    }
  }
  // reduce over the 16 lanes (ln) holding different v
  #pragma unroll
  for (int m = 1; m < 16; m <<= 1) {
    #pragma unroll
    for (int mt = 0; mt < 2; mt++) {
      #pragma unroll
      for (int r = 0; r < 4; r++) {
        const float ov = __shfl_xor(bv[mt][r], m, 64);
        const int oi = __shfl_xor(bi[mt][r], m, 64);
        if (ov > bv[mt][r] || (ov == bv[mt][r] && oi < bi[mt][r])) {
          bv[mt][r] = ov; bi[mt][r] = oi;
        }
      }
    }
  }
  __shared__ float lv[128];
  __shared__ int li[128];
  if (ln == 0) {
    #pragma unroll
    for (int mt = 0; mt < 2; mt++)
      for (int r = 0; r < 4; r++) {
        const int b = mt * 16 + quad * 4 + r;
        lv[w * 32 + b] = bv[mt][r];
        li[w * 32 + b] = bi[mt][r];
      }
  }
  __syncthreads();
  if (tid < 32) {
    float bbv = lv[tid]; int bbi = li[tid];
    for (int w2 = 1; w2 < 4; w2++) {           // ascending wave -> ascending v
      const float ov = lv[w2 * 32 + tid]; const int oi = li[w2 * 32 + tid];
      if (ov > bbv || (ov == bbv && oi < bbi)) { bbv = ov; bbi = oi; }
    }
    pval[tid * 128 + blockIdx.x] = bbv;
    pidx[tid * 128 + blockIdx.x] = bbi;
  }
}

// ---------------------------------------------------------------------------
extern "C" void kernel_launch(void* const* d_in, const int* in_sizes, int n_in,
                              void* d_out, int out_size, void* d_ws, size_t ws_size,
                              hipStream_t stream) {
  const float* enc = (const float*)d_in[0];
  const int* sos = (const int*)d_in[2];
  const float* emb = (const float*)d_in[3];
  const float* W1 = (const float*)d_in[4];
  const float* b1 = (const float*)d_in[5];
  const float* W2 = (const float*)d_in[6];
  const float* b2 = (const float*)d_in[7];
  const float* Wih = (const float*)d_in[8];
  const float* bih = (const float*)d_in[9];
  const float* Whh = (const float*)d_in[10];
  const float* bhh = (const float*)d_in[11];
  const float* Wo = (const float*)d_in[12];
  const float* bo = (const float*)d_in[13];

  char* ws = (char*)d_ws;
  // parity-0 state block is contiguous for a single init: hf0|hh0|hl0
  float* hf[2]  = {(float*)(ws + 0),       (float*)(ws + 131072)};
  __bf16* hh[2] = {(__bf16*)(ws + 65536),  (__bf16*)(ws + 196608)};
  __bf16* hl[2] = {(__bf16*)(ws + 98304),  (__bf16*)(ws + 229376)};
  __bf16* xh = (__bf16*)(ws + 262144);
  __bf16* xl = (__bf16*)(ws + 344064);
  float* encW1 = (float*)(ws + 425984);
  float* pval = (float*)(ws + 950272);
  int* pidx = (int*)(ws + 966656);

  k_init<<<128, 256, 0, stream>>>((unsigned int*)ws);   // h state = 0
  k_encw1<<<S_LEN * BATCH, 256, 0, stream>>>(enc, W1, encW1);

  float* out = (float*)d_out;
  for (int t = 0; t < TMAX; t++) {
    const int p = t & 1;
    k_attn<<<BATCH, 256, 0, stream>>>(t, enc, sos, emb, W1, b1, W2, b2,
                                      encW1, hf[p], pval, pidx, xh, xl);
    k_gru<<<32, 256, 0, stream>>>(xh, xl, Wih, bih, Whh, bhh,
                                  hf[p], hh[p], hl[p],
                                  hf[p ^ 1], hh[p ^ 1], hl[p ^ 1]);
    k_logits<<<NCHUNK, 256, 0, stream>>>(hh[p ^ 1], hl[p ^ 1], Wo, bo,
                                         out + (size_t)t * BATCH * VOC, pval, pidx);
  }
}